// Round 4
// baseline (148.228 us; speedup 1.0000x reference)
//
#include <hip/hip_runtime.h>
#include <hip/hip_bf16.h>

typedef __attribute__((ext_vector_type(4))) float f32x4;
typedef __attribute__((ext_vector_type(8))) __bf16 bf16x8;
typedef __attribute__((ext_vector_type(4))) unsigned int u32x4;

// B=32, S=4096, E=A=512.
// out = [weighted (32*512), prob (32*4096)] fp32, total 147456.

// ---------- prep 1: fragment-ordered bf16 W_enc^T ----------
// Wf[((ntile*16 + kb)*64 + lane)*8 + j] = bf16(W_enc[kb*32 + (lane>>4)*8 + j][ntile*16 + (lane&15)])
__global__ void prep_w(const float* __restrict__ W_enc, unsigned short* __restrict__ Wf) {
  int idx = blockIdx.x * 256 + threadIdx.x;   // 0..32767
  int lane = idx & 63;
  int grp = idx >> 6;                         // ntile*16 + kb
  int ntile = grp >> 4, kb = grp & 15;
  int n = ntile * 16 + (lane & 15);
  int k0 = kb * 32 + (lane >> 4) * 8;
  unsigned short* dst = Wf + idx * 8;
  #pragma unroll
  for (int j = 0; j < 8; ++j) {
    float f = W_enc[(k0 + j) * 512 + n];
    dst[j] = __builtin_bit_cast(unsigned short, (__bf16)f);
  }
}

// ---------- prep 2 (k-split x4): cpart[j][b][a] = partial dec_h@W_dec (+biases in j==0) ----------
__global__ void prep_c(const float* __restrict__ dec_h, const float* __restrict__ W_dec,
                       const float* __restrict__ b_dec, const float* __restrict__ b_enc,
                       float* __restrict__ cpart) {
  int b = blockIdx.x >> 2, j = blockIdx.x & 3;
  int a = threadIdx.x;                        // 512 threads
  const float* dh = dec_h + b * 512 + j * 128;
  const float* wd = W_dec + (j * 128) * 512 + a;
  float s = (j == 0) ? (b_dec[a] + b_enc[a]) : 0.f;
  #pragma unroll 8
  for (int k = 0; k < 128; ++k) s += dh[k] * wd[k * 512];
  cpart[j * 16384 + b * 512 + a] = s;
}

// ---------- main: persistent, 1024 threads (16 waves), 1 block/CU, 8 chunks of 64 rows,
// ---------- async-STAGE: issue loads(i+1) -> GEMM(i) -> epilogue/pw(i) -> write(i+1) ----------
__global__ __launch_bounds__(1024, 4) void attn_main(
    const float* __restrict__ input, const unsigned short* __restrict__ Wf,
    const float* __restrict__ cpart, const float* __restrict__ w_att,
    float* __restrict__ att_out, float* __restrict__ m_out, float* __restrict__ pw_out) {
  __shared__ u32x4 A4[4096];                 // 64 rows x 512 bf16, XOR-swizzled (64 KB)
  __shared__ float c_lds[512];
  __shared__ float w_lds[512];
  __shared__ float red[16][64];
  __shared__ float p_lds[64];

  char* Al = (char*)A4;
  const int tid = threadIdx.x;
  const int wave = tid >> 6, lane = tid & 63;
  const int l15 = lane & 15, l4 = lane >> 4;
  const int blk = blockIdx.x;                // 256 blocks
  const int ci0 = blk * 8;                   // 8 chunks per block, 2048 chunks total
  const int b = ci0 >> 6;                    // 64 chunks per batch

  if (tid < 512) {
    c_lds[tid] = cpart[tid + b * 512] + cpart[16384 + tid + b * 512]
               + cpart[32768 + tid + b * 512] + cpart[49152 + tid + b * 512];
    w_lds[tid] = w_att[tid];
  }

  float4 fa[4][2];                           // in-flight staging regs (32 VGPR)

  auto LOADS = [&](int ci) {
    const float* base = input + (long)ci * 32768;   // 64 rows * 512
    #pragma unroll
    for (int u = 0; u < 4; ++u) {
      int ch = tid + u * 1024;               // 8-float units, 0..4095
      int row = ch >> 6, c32 = ch & 63;
      const float4* s4 = (const float4*)(base + row * 512 + c32 * 8);   // FIX: *8, was *16 (OOB)
      fa[u][0] = s4[0];
      fa[u][1] = s4[1];
    }
  };
  auto WRITECONV = [&]() {
    #pragma unroll
    for (int u = 0; u < 4; ++u) {
      int ch = tid + u * 1024;
      int row = ch >> 6, c32 = ch & 63;
      bf16x8 v;
      v[0] = (__bf16)fa[u][0].x; v[1] = (__bf16)fa[u][0].y;
      v[2] = (__bf16)fa[u][0].z; v[3] = (__bf16)fa[u][0].w;
      v[4] = (__bf16)fa[u][1].x; v[5] = (__bf16)fa[u][1].y;
      v[6] = (__bf16)fa[u][1].z; v[7] = (__bf16)fa[u][1].w;
      *(bf16x8*)(Al + row * 1024 + ((c32 * 16) ^ ((row & 7) << 4))) = v;   // 16 LDS bytes/unit
    }
  };

  const bf16x8* Wfp = (const bf16x8*)Wf;
  const int w2 = wave * 2;
  const bf16x8* wbase = Wfp + (w2 * 16) * 64 + lane;   // +kb*64 per step; +16*64 for nj=1

  // prologue: stage chunk 0
  LOADS(ci0);
  WRITECONV();
  __syncthreads();

  for (int i = 0; i < 8; ++i) {
    const int ci = ci0 + i;
    if (i < 7) LOADS(ci + 1);                // in flight across GEMM+epilogue

    // ---- GEMM: wave covers n-tiles w2, w2+1; rows 0..63 ----
    f32x4 acc[4][2];
    #pragma unroll
    for (int mi = 0; mi < 4; ++mi) {
      f32x4 z = {0.f, 0.f, 0.f, 0.f};
      acc[mi][0] = z; acc[mi][1] = z;
    }
    #pragma unroll 4
    for (int kb = 0; kb < 16; ++kb) {
      bf16x8 bv0 = wbase[kb * 64];
      bf16x8 bv1 = wbase[(16 + kb) * 64];
      #pragma unroll
      for (int mi = 0; mi < 4; ++mi) {
        int row = mi * 16 + l15;
        bf16x8 afr = *(const bf16x8*)(Al + row * 1024 + (((kb * 64) + l4 * 16) ^ ((row & 7) << 4)));
        acc[mi][0] = __builtin_amdgcn_mfma_f32_16x16x32_bf16(afr, bv0, acc[mi][0], 0, 0, 0);
        acc[mi][1] = __builtin_amdgcn_mfma_f32_16x16x32_bf16(afr, bv1, acc[mi][1], 0, 0, 0);
      }
    }

    // ---- epilogue: att[row] = sum_n relu(enc_att + c[n]) * w[n] ----
    float attp[16];
    #pragma unroll
    for (int q = 0; q < 16; ++q) attp[q] = 0.f;
    #pragma unroll
    for (int nj = 0; nj < 2; ++nj) {
      int n = (w2 + nj) * 16 + l15;
      float cc = c_lds[n], ww = w_lds[n];
      #pragma unroll
      for (int mi = 0; mi < 4; ++mi)
        #pragma unroll
        for (int r = 0; r < 4; ++r)
          attp[mi * 4 + r] += fmaxf(acc[mi][nj][r] + cc, 0.f) * ww;
    }
    #pragma unroll
    for (int off = 1; off < 16; off <<= 1)
      #pragma unroll
      for (int q = 0; q < 16; ++q)
        attp[q] += __shfl_xor(attp[q], off, 64);
    if (l15 == 0) {
      #pragma unroll
      for (int mi = 0; mi < 4; ++mi)
        #pragma unroll
        for (int r = 0; r < 4; ++r)
          red[wave][mi * 16 + l4 * 4 + r] = attp[mi * 4 + r];
    }
    __syncthreads();

    if (tid < 64) {
      float av = 0.f;
      #pragma unroll
      for (int w = 0; w < 16; ++w) av += red[w][tid];
      att_out[b * 4096 + (ci & 63) * 64 + tid] = av;   // b_att omitted: cancels in softmax
      float m = av;
      #pragma unroll
      for (int off = 32; off >= 1; off >>= 1) m = fmaxf(m, __shfl_xor(m, off, 64));
      p_lds[tid] = expf(av - m);
      if (tid == 0) m_out[ci] = m;
    }
    __syncthreads();

    // ---- pw[e] = sum_s exp(att_s - m_blk) * input[s][e] (bf16 from LDS) ----
    {
      int col = tid >> 1, h = tid & 1;
      int ebyte = (col >> 1) * 4;
      unsigned int sh = (col & 1) ? 0u : 16u;
      float pwa = 0.f;
      #pragma unroll 8
      for (int s = h * 32; s < h * 32 + 32; ++s) {
        float p = p_lds[s];
        unsigned int u = *(const unsigned int*)(Al + s * 1024 + (ebyte ^ ((s & 7) << 4)));
        pwa += p * __builtin_bit_cast(float, (u << sh) & 0xffff0000u);
      }
      pwa += __shfl_xor(pwa, 1, 64);
      if (h == 0) pw_out[ci * 512 + col] = pwa;
    }
    __syncthreads();                          // all reads of A-tile done

    if (i < 7) WRITECONV();                   // vmcnt drains here; loads had full chunk to land
    __syncthreads();
  }
}

// ---------- finalize: per-batch global softmax + rescaled partial-sum reduction ----------
__global__ void finalize(const float* __restrict__ att, const float* __restrict__ m_blk,
                         const float* __restrict__ pw, float* __restrict__ out) {
  const int bg = blockIdx.x;                 // 128 blocks = 32 b x 4 groups
  const int b = bg >> 2, g = bg & 3;
  const int tid = threadIdx.x;               // 256
  const int wave = tid >> 6, lane = tid & 63;
  __shared__ float wred[4];
  __shared__ float zred[4];
  __shared__ float fac[64];

  float v[16];
  float mx = -3.4e38f;
  #pragma unroll
  for (int i = 0; i < 16; ++i) {
    v[i] = att[b * 4096 + i * 256 + tid];
    mx = fmaxf(mx, v[i]);
  }
  #pragma unroll
  for (int off = 32; off >= 1; off >>= 1) mx = fmaxf(mx, __shfl_xor(mx, off, 64));
  if (lane == 0) wred[wave] = mx;
  __syncthreads();
  mx = fmaxf(fmaxf(wred[0], wred[1]), fmaxf(wred[2], wred[3]));

  float z = 0.f;
  #pragma unroll
  for (int i = 0; i < 16; ++i) { v[i] = expf(v[i] - mx); z += v[i]; }
  #pragma unroll
  for (int off = 32; off >= 1; off >>= 1) z += __shfl_xor(z, off, 64);
  if (lane == 0) zred[wave] = z;
  __syncthreads();
  z = zred[0] + zred[1] + zred[2] + zred[3];
  float invZ = 1.f / z;

  #pragma unroll
  for (int i = 0; i < 4; ++i) {
    int ii = g * 4 + i;
    out[16384 + b * 4096 + ii * 256 + tid] = v[ii] * invZ;   // prob (this block's quarter)
  }

  if (tid < 64) fac[tid] = expf(m_blk[b * 64 + tid] - mx) * invZ;
  __syncthreads();

  int col = g * 128 + (tid >> 1);
  int h = tid & 1;
  float w0 = 0.f;
  #pragma unroll 8
  for (int s = h * 32; s < h * 32 + 32; ++s)
    w0 += fac[s] * pw[(b * 64 + s) * 512 + col];
  w0 += __shfl_xor(w0, 1, 64);
  if (h == 0) out[b * 512 + col] = w0;                       // weighted
}

extern "C" void kernel_launch(void* const* d_in, const int* in_sizes, int n_in,
                              void* d_out, int out_size, void* d_ws, size_t ws_size,
                              hipStream_t stream) {
  const float* input = (const float*)d_in[0];
  const float* dec_h = (const float*)d_in[1];
  const float* W_enc = (const float*)d_in[2];
  const float* b_enc = (const float*)d_in[3];
  const float* W_dec = (const float*)d_in[4];
  const float* b_dec = (const float*)d_in[5];
  const float* w_att = (const float*)d_in[6];
  // d_in[7] = b_att: constant shift of logits, cancels in softmax.
  float* out = (float*)d_out;

  char* ws = (char*)d_ws;
  unsigned short* Wf = (unsigned short*)(ws);           // 512 KB  fragment-ordered bf16 W_enc^T
  float* cpart = (float*)(ws + 524288);                 // 256 KB  dec_att partials [4][32][512]
  float* att   = (float*)(ws + 786432);                 // 512 KB  logits [32][4096]
  float* m_b   = (float*)(ws + 1310720);                // 8 KB    per-chunk max [2048]
  float* pw    = (float*)(ws + 1318912);                // 4 MB    partial weighted [2048][512]

  hipLaunchKernelGGL(prep_w, dim3(128), dim3(256), 0, stream, W_enc, Wf);
  hipLaunchKernelGGL(prep_c, dim3(128), dim3(512), 0, stream, dec_h, W_dec, b_dec, b_enc, cpart);
  hipLaunchKernelGGL(attn_main, dim3(256), dim3(1024), 0, stream, input, Wf, cpart, w_att, att, m_b, pw);
  hipLaunchKernelGGL(finalize, dim3(128), dim3(256), 0, stream, att, m_b, pw, out);
}

// Round 5
// 145.163 us; speedup vs baseline: 1.0211x; 1.0211x over previous
//
#include <hip/hip_runtime.h>
#include <hip/hip_bf16.h>

typedef __attribute__((ext_vector_type(4))) float f32x4;
typedef __attribute__((ext_vector_type(8))) __bf16 bf16x8;
typedef __attribute__((ext_vector_type(4))) unsigned int u32x4;

// B=32, S=4096, E=A=512.
// out = [weighted (32*512), prob (32*4096)] fp32, total 147456.

__device__ __forceinline__ float lo_bf(unsigned int u) {
  return __builtin_bit_cast(float, u << 16);
}
__device__ __forceinline__ float hi_bf(unsigned int u) {
  return __builtin_bit_cast(float, u & 0xffff0000u);
}

// Raw barrier: drain LDS ops only — vmcnt (global loads/stores) stays in flight.
__device__ __forceinline__ void barrier_lgkm() {
  asm volatile("s_waitcnt lgkmcnt(0)" ::: "memory");
  __builtin_amdgcn_s_barrier();
  asm volatile("" ::: "memory");
}

// ---------- prep 1: fragment-ordered bf16 W_enc^T ----------
// Wf[((nt*16 + kb)*64 + lane)*8 + j] = bf16(W_enc[kb*32 + (lane>>4)*8 + j][nt*16 + (lane&15)])
__global__ void prep_w(const float* __restrict__ W_enc, unsigned short* __restrict__ Wf) {
  int idx = blockIdx.x * 256 + threadIdx.x;   // 0..32767
  int lane = idx & 63;
  int grp = idx >> 6;                         // nt*16 + kb
  int nt = grp >> 4, kb = grp & 15;
  int n = nt * 16 + (lane & 15);
  int k0 = kb * 32 + (lane >> 4) * 8;
  unsigned short* dst = Wf + idx * 8;
  #pragma unroll
  for (int j = 0; j < 8; ++j) {
    float f = W_enc[(k0 + j) * 512 + n];
    dst[j] = __builtin_bit_cast(unsigned short, (__bf16)f);
  }
}

// ---------- prep 2 (k-split x4): cpart[j][b][a] = partial dec_h@W_dec (+biases in j==0) ----------
__global__ void prep_c(const float* __restrict__ dec_h, const float* __restrict__ W_dec,
                       const float* __restrict__ b_dec, const float* __restrict__ b_enc,
                       float* __restrict__ cpart) {
  int b = blockIdx.x >> 2, j = blockIdx.x & 3;
  int a = threadIdx.x;                        // 512 threads
  const float* dh = dec_h + b * 512 + j * 128;
  const float* wd = W_dec + (j * 128) * 512 + a;
  float s = (j == 0) ? (b_dec[a] + b_enc[a]) : 0.f;
  #pragma unroll 8
  for (int k = 0; k < 128; ++k) s += dh[k] * wd[k * 512];
  cpart[j * 16384 + b * 512 + a] = s;
}

// ---------- main: 512 thr / 8 waves / 1 block/CU. Waves 0-3 compute, waves 4-7 stage.
// ---------- Double-buffered LDS A-tile; raw lgkm barriers keep stage loads in flight. ----------
__global__ __launch_bounds__(512, 2) void attn_main(
    const float* __restrict__ input, const unsigned short* __restrict__ Wf,
    const float* __restrict__ cpart, const float* __restrict__ w_att,
    float* __restrict__ att_out, float* __restrict__ m_out, float* __restrict__ pw_out) {
  __shared__ u32x4 A4[8192];                 // 2 x (64 rows x 512 bf16), XOR-swizzled (128 KB)
  __shared__ float c_lds[512];
  __shared__ float w_lds[512];
  __shared__ float red[4][64];
  __shared__ float redf[512];
  __shared__ float p_lds[64];

  char* Al = (char*)A4;
  const int tid = threadIdx.x;
  const int wave = tid >> 6, lane = tid & 63;
  const int l15 = lane & 15, l4 = lane >> 4;
  const int blk = blockIdx.x;                // 256 blocks, 1 per CU
  const int ci0 = blk * 8;                   // 8 chunks of 64 rows per block
  const int b = ci0 >> 6;                    // batch (all 8 chunks in same batch)

  // stage: producer waves 4-7 (256 threads) convert one 64x512 fp32 chunk -> bf16 LDS buf
  auto STAGE = [&](int ci, int bufsel) {
    const float* base = input + (long)ci * 32768;
    char* dst = Al + bufsel * 65536;
    const int st = tid & 255;
    #pragma unroll
    for (int half = 0; half < 2; ++half) {
      float4 g[8][2];
      #pragma unroll
      for (int j = 0; j < 8; ++j) {
        int ch = st + (half * 8 + j) * 256;  // 8-float units, 0..4095
        int row = ch >> 6, c32 = ch & 63;
        const float4* s4 = (const float4*)(base + row * 512 + c32 * 8);
        g[j][0] = s4[0];
        g[j][1] = s4[1];
      }
      #pragma unroll
      for (int j = 0; j < 8; ++j) {
        int ch = st + (half * 8 + j) * 256;
        int row = ch >> 6, c32 = ch & 63;
        bf16x8 v;
        v[0] = (__bf16)g[j][0].x; v[1] = (__bf16)g[j][0].y;
        v[2] = (__bf16)g[j][0].z; v[3] = (__bf16)g[j][0].w;
        v[4] = (__bf16)g[j][1].x; v[5] = (__bf16)g[j][1].y;
        v[6] = (__bf16)g[j][1].z; v[7] = (__bf16)g[j][1].w;
        *(bf16x8*)(dst + row * 1024 + ((c32 * 16) ^ ((row & 7) << 4))) = v;
      }
    }
  };

  // prologue: compute waves fetch c/w; stage waves stage chunk 0 into buf 0
  if (wave < 4) {
    for (int q = tid; q < 512; q += 256) {
      c_lds[q] = cpart[b * 512 + q] + cpart[16384 + b * 512 + q]
               + cpart[32768 + b * 512 + q] + cpart[49152 + b * 512 + q];
      w_lds[q] = w_att[q];
    }
  } else {
    STAGE(ci0, 0);
  }
  barrier_lgkm();

  const bf16x8* Wfp = (const bf16x8*)Wf;
  int cur = 0;

  for (int i = 0; i < 8; ++i) {
    const int ci = ci0 + i;
    const char* Ab = Al + cur * 65536;

    if (wave < 4) {
      // ---- K-loop: wave covers n-tiles wave*8 .. wave*8+7, rows 0..63 ----
      f32x4 acc[4][8];
      #pragma unroll
      for (int mi = 0; mi < 4; ++mi)
        #pragma unroll
        for (int nj = 0; nj < 8; ++nj) {
          f32x4 z = {0.f, 0.f, 0.f, 0.f};
          acc[mi][nj] = z;
        }
      #pragma unroll 2
      for (int kb = 0; kb < 16; ++kb) {
        bf16x8 bv[8];
        #pragma unroll
        for (int nj = 0; nj < 8; ++nj)
          bv[nj] = Wfp[((wave * 8 + nj) * 16 + kb) * 64 + lane];
        #pragma unroll
        for (int mi = 0; mi < 4; ++mi) {
          int row = mi * 16 + l15;
          bf16x8 afr = *(const bf16x8*)(Ab + row * 1024 + (((kb * 64) + l4 * 16) ^ ((row & 7) << 4)));
          #pragma unroll
          for (int nj = 0; nj < 8; ++nj)
            acc[mi][nj] = __builtin_amdgcn_mfma_f32_16x16x32_bf16(afr, bv[nj], acc[mi][nj], 0, 0, 0);
        }
      }
      // ---- epilogue: att[row] = sum_n relu(enc_att + c[n]) * w[n] ----
      float attp[16];
      #pragma unroll
      for (int q = 0; q < 16; ++q) attp[q] = 0.f;
      #pragma unroll
      for (int nj = 0; nj < 8; ++nj) {
        int n = (wave * 8 + nj) * 16 + l15;
        float cc = c_lds[n], ww = w_lds[n];
        #pragma unroll
        for (int mi = 0; mi < 4; ++mi)
          #pragma unroll
          for (int r = 0; r < 4; ++r)
            attp[mi * 4 + r] += fmaxf(acc[mi][nj][r] + cc, 0.f) * ww;
      }
      #pragma unroll
      for (int off = 1; off < 16; off <<= 1)
        #pragma unroll
        for (int q = 0; q < 16; ++q)
          attp[q] += __shfl_xor(attp[q], off, 64);
      if (l15 == 0) {
        #pragma unroll
        for (int mi = 0; mi < 4; ++mi)
          #pragma unroll
          for (int r = 0; r < 4; ++r)
            red[wave][mi * 16 + l4 * 4 + r] = attp[mi * 4 + r];
      }
    } else if (i < 7) {
      STAGE(ci + 1, cur ^ 1);                // producer: next chunk into other buffer
    }
    barrier_lgkm();

    if (tid < 64) {
      float av = red[0][tid] + red[1][tid] + red[2][tid] + red[3][tid];
      att_out[b * 4096 + (ci & 63) * 64 + tid] = av;   // b_att omitted: cancels in softmax
      float m = av;
      #pragma unroll
      for (int off = 32; off >= 1; off >>= 1) m = fmaxf(m, __shfl_xor(m, off, 64));
      p_lds[tid] = expf(av - m);
      if (tid == 0) m_out[ci] = m;
    }
    barrier_lgkm();

    // ---- pw[e] = sum_s exp(att_s - m_blk) * input[s][e] (bf16 from LDS, all 8 waves) ----
    {
      int c = tid & 255, h = tid >> 8;       // cols (2c,2c+1), row half h
      float pw0 = 0.f, pw1 = 0.f;
      #pragma unroll 8
      for (int s = h * 32; s < h * 32 + 32; ++s) {
        float p = p_lds[s];
        unsigned int u = *(const unsigned int*)(Ab + s * 1024 + ((c * 4) ^ ((s & 7) << 4)));
        pw0 += p * lo_bf(u);
        pw1 += p * hi_bf(u);
      }
      if (h == 1) { redf[c * 2] = pw0; redf[c * 2 + 1] = pw1; }
      barrier_lgkm();
      if (h == 0) {
        pw_out[ci * 512 + c * 2]     = pw0 + redf[c * 2];
        pw_out[ci * 512 + c * 2 + 1] = pw1 + redf[c * 2 + 1];
      }
    }
    cur ^= 1;
  }
}

// ---------- finalize: per-batch global softmax + rescaled partial-sum reduction ----------
__global__ void finalize(const float* __restrict__ att, const float* __restrict__ m_blk,
                         const float* __restrict__ pw, float* __restrict__ out) {
  const int bg = blockIdx.x;                 // 128 blocks = 32 b x 4 groups
  const int b = bg >> 2, g = bg & 3;
  const int tid = threadIdx.x;               // 256
  const int wave = tid >> 6, lane = tid & 63;
  __shared__ float wred[4];
  __shared__ float zred[4];
  __shared__ float fac[64];

  float v[16];
  float mx = -3.4e38f;
  #pragma unroll
  for (int i = 0; i < 16; ++i) {
    v[i] = att[b * 4096 + i * 256 + tid];
    mx = fmaxf(mx, v[i]);
  }
  #pragma unroll
  for (int off = 32; off >= 1; off >>= 1) mx = fmaxf(mx, __shfl_xor(mx, off, 64));
  if (lane == 0) wred[wave] = mx;
  __syncthreads();
  mx = fmaxf(fmaxf(wred[0], wred[1]), fmaxf(wred[2], wred[3]));

  float z = 0.f;
  #pragma unroll
  for (int i = 0; i < 16; ++i) { v[i] = expf(v[i] - mx); z += v[i]; }
  #pragma unroll
  for (int off = 32; off >= 1; off >>= 1) z += __shfl_xor(z, off, 64);
  if (lane == 0) zred[wave] = z;
  __syncthreads();
  z = zred[0] + zred[1] + zred[2] + zred[3];
  float invZ = 1.f / z;

  #pragma unroll
  for (int i = 0; i < 4; ++i) {
    int ii = g * 4 + i;
    out[16384 + b * 4096 + ii * 256 + tid] = v[ii] * invZ;   // prob (this block's quarter)
  }

  if (tid < 64) fac[tid] = expf(m_blk[b * 64 + tid] - mx) * invZ;
  __syncthreads();

  int col = g * 128 + (tid >> 1);
  int h = tid & 1;
  float w0 = 0.f;
  #pragma unroll 8
  for (int s = h * 32; s < h * 32 + 32; ++s)
    w0 += fac[s] * pw[(b * 64 + s) * 512 + col];
  w0 += __shfl_xor(w0, 1, 64);
  if (h == 0) out[b * 512 + col] = w0;                       // weighted
}

extern "C" void kernel_launch(void* const* d_in, const int* in_sizes, int n_in,
                              void* d_out, int out_size, void* d_ws, size_t ws_size,
                              hipStream_t stream) {
  const float* input = (const float*)d_in[0];
  const float* dec_h = (const float*)d_in[1];
  const float* W_enc = (const float*)d_in[2];
  const float* b_enc = (const float*)d_in[3];
  const float* W_dec = (const float*)d_in[4];
  const float* b_dec = (const float*)d_in[5];
  const float* w_att = (const float*)d_in[6];
  // d_in[7] = b_att: constant shift of logits, cancels in softmax.
  float* out = (float*)d_out;

  char* ws = (char*)d_ws;
  unsigned short* Wf = (unsigned short*)(ws);           // 512 KB  fragment-ordered bf16 W_enc^T
  float* cpart = (float*)(ws + 524288);                 // 256 KB  dec_att partials [4][32][512]
  float* att   = (float*)(ws + 786432);                 // 512 KB  logits [32][4096]
  float* m_b   = (float*)(ws + 1310720);                // 8 KB    per-chunk max [2048]
  float* pw    = (float*)(ws + 1318912);                // 4 MB    partial weighted [2048][512]

  hipLaunchKernelGGL(prep_w, dim3(128), dim3(256), 0, stream, W_enc, Wf);
  hipLaunchKernelGGL(prep_c, dim3(128), dim3(512), 0, stream, dec_h, W_dec, b_dec, b_enc, cpart);
  hipLaunchKernelGGL(attn_main, dim3(256), dim3(512), 0, stream, input, Wf, cpart, w_att, att, m_b, pw);
  hipLaunchKernelGGL(finalize, dim3(128), dim3(256), 0, stream, att, m_b, pw, out);
}

// Round 6
// 132.077 us; speedup vs baseline: 1.1223x; 1.0991x over previous
//
#include <hip/hip_runtime.h>
#include <hip/hip_bf16.h>

typedef __attribute__((ext_vector_type(4))) float f32x4;
typedef __attribute__((ext_vector_type(8))) __bf16 bf16x8;
typedef __attribute__((ext_vector_type(4))) unsigned int u32x4;

// B=32, S=4096, E=A=512.
// out = [weighted (32*512), prob (32*4096)] fp32, total 147456.

__device__ __forceinline__ float lo_bf(unsigned int u) {
  return __builtin_bit_cast(float, u << 16);
}
__device__ __forceinline__ float hi_bf(unsigned int u) {
  return __builtin_bit_cast(float, u & 0xffff0000u);
}

// Raw barrier: drain LDS ops only — vmcnt (global loads/stores) stays in flight.
__device__ __forceinline__ void barrier_lgkm() {
  asm volatile("s_waitcnt lgkmcnt(0)" ::: "memory");
  __builtin_amdgcn_s_barrier();
  asm volatile("" ::: "memory");
}

// ---------- prep 1: fragment-ordered bf16 W_enc^T ----------
// Wf[((nt*16 + kb)*64 + lane)*8 + j] = bf16(W_enc[kb*32 + (lane>>4)*8 + j][nt*16 + (lane&15)])
__global__ void prep_w(const float* __restrict__ W_enc, unsigned short* __restrict__ Wf) {
  int idx = blockIdx.x * 256 + threadIdx.x;   // 0..32767
  int lane = idx & 63;
  int grp = idx >> 6;                         // nt*16 + kb
  int nt = grp >> 4, kb = grp & 15;
  int n = nt * 16 + (lane & 15);
  int k0 = kb * 32 + (lane >> 4) * 8;
  unsigned short* dst = Wf + idx * 8;
  #pragma unroll
  for (int j = 0; j < 8; ++j) {
    float f = W_enc[(k0 + j) * 512 + n];
    dst[j] = __builtin_bit_cast(unsigned short, (__bf16)f);
  }
}

// ---------- prep 2 (k-split x4): cpart[j][b][a] = partial dec_h@W_dec (+biases in j==0) ----------
__global__ void prep_c(const float* __restrict__ dec_h, const float* __restrict__ W_dec,
                       const float* __restrict__ b_dec, const float* __restrict__ b_enc,
                       float* __restrict__ cpart) {
  int b = blockIdx.x >> 2, j = blockIdx.x & 3;
  int a = threadIdx.x;                        // 512 threads
  const float* dh = dec_h + b * 512 + j * 128;
  const float* wd = W_dec + (j * 128) * 512 + a;
  float s = (j == 0) ? (b_dec[a] + b_enc[a]) : 0.f;
  #pragma unroll 8
  for (int k = 0; k < 128; ++k) s += dh[k] * wd[k * 512];
  cpart[j * 16384 + b * 512 + a] = s;
}

// ---------- main: 1024 thr / 16 waves / 1 block/CU. Waves 0-7 compute, 8-15 stage.
// ---------- 2 compute + 2 stage waves per SIMD: L2/HBM latency hidden by co-resident MFMA. ----------
__global__ __launch_bounds__(1024, 4) void attn_main(
    const float* __restrict__ input, const unsigned short* __restrict__ Wf,
    const float* __restrict__ cpart, const float* __restrict__ w_att,
    float* __restrict__ att_out, float* __restrict__ m_out, float* __restrict__ pw_out) {
  __shared__ u32x4 A4[8192];                 // 2 x (64 rows x 512 bf16), XOR-swizzled (128 KB)
  __shared__ float c_lds[512];
  __shared__ float w_lds[512];
  __shared__ float red[8][64];
  __shared__ float redf[512];
  __shared__ float p_lds[64];

  char* Al = (char*)A4;
  const int tid = threadIdx.x;
  const int wave = tid >> 6, lane = tid & 63;
  const int l15 = lane & 15, l4 = lane >> 4;
  const int blk = blockIdx.x;                // 256 blocks, 1 per CU
  const int ci0 = blk * 8;                   // 8 chunks of 64 rows per block
  const int b = ci0 >> 6;                    // batch (all 8 chunks in same batch)

  // stage: producer waves 8-15 (512 threads) convert one 64x512 fp32 chunk -> bf16 LDS buf
  auto STAGE = [&](int ci, int bufsel) {
    const float* base = input + (long)ci * 32768;
    char* dst = Al + bufsel * 65536;
    const int st = tid & 511;
    #pragma unroll
    for (int half = 0; half < 2; ++half) {
      float4 g[4][2];
      #pragma unroll
      for (int j = 0; j < 4; ++j) {
        int ch = st + (half * 4 + j) * 512;  // 8-float units, 0..4095
        int row = ch >> 6, c32 = ch & 63;
        const float4* s4 = (const float4*)(base + row * 512 + c32 * 8);
        g[j][0] = s4[0];
        g[j][1] = s4[1];
      }
      #pragma unroll
      for (int j = 0; j < 4; ++j) {
        int ch = st + (half * 4 + j) * 512;
        int row = ch >> 6, c32 = ch & 63;
        bf16x8 v;
        v[0] = (__bf16)g[j][0].x; v[1] = (__bf16)g[j][0].y;
        v[2] = (__bf16)g[j][0].z; v[3] = (__bf16)g[j][0].w;
        v[4] = (__bf16)g[j][1].x; v[5] = (__bf16)g[j][1].y;
        v[6] = (__bf16)g[j][1].z; v[7] = (__bf16)g[j][1].w;
        *(bf16x8*)(dst + row * 1024 + ((c32 * 16) ^ ((row & 7) << 4))) = v;
      }
    }
  };

  // prologue: compute waves fetch c/w; stage waves stage chunk 0 into buf 0
  if (wave < 8) {
    c_lds[tid] = cpart[b * 512 + tid] + cpart[16384 + b * 512 + tid]
               + cpart[32768 + b * 512 + tid] + cpart[49152 + b * 512 + tid];
    w_lds[tid] = w_att[tid];
  } else {
    STAGE(ci0, 0);
  }
  barrier_lgkm();

  const bf16x8* Wfp = (const bf16x8*)Wf;
  int cur = 0;

  for (int i = 0; i < 8; ++i) {
    const int ci = ci0 + i;
    const char* Ab = Al + cur * 65536;

    if (wave < 8) {
      // ---- K-loop: wave covers n-tiles wave*4 .. wave*4+3, rows 0..63 ----
      f32x4 acc[4][4];
      #pragma unroll
      for (int mi = 0; mi < 4; ++mi)
        #pragma unroll
        for (int nj = 0; nj < 4; ++nj) {
          f32x4 z = {0.f, 0.f, 0.f, 0.f};
          acc[mi][nj] = z;
        }
      const bf16x8* wb = Wfp + (wave * 4 * 16) * 64 + lane;
      #pragma unroll 2
      for (int kb = 0; kb < 16; ++kb) {
        bf16x8 bv[4];
        #pragma unroll
        for (int nj = 0; nj < 4; ++nj)
          bv[nj] = wb[(nj * 16 + kb) * 64];
        __builtin_amdgcn_s_setprio(1);
        #pragma unroll
        for (int mi = 0; mi < 4; ++mi) {
          int row = mi * 16 + l15;
          bf16x8 afr = *(const bf16x8*)(Ab + row * 1024 + (((kb * 64) + l4 * 16) ^ ((row & 7) << 4)));
          #pragma unroll
          for (int nj = 0; nj < 4; ++nj)
            acc[mi][nj] = __builtin_amdgcn_mfma_f32_16x16x32_bf16(afr, bv[nj], acc[mi][nj], 0, 0, 0);
        }
        __builtin_amdgcn_s_setprio(0);
      }
      // ---- epilogue: att[row] = sum_n relu(enc_att + c[n]) * w[n] ----
      float attp[16];
      #pragma unroll
      for (int q = 0; q < 16; ++q) attp[q] = 0.f;
      #pragma unroll
      for (int nj = 0; nj < 4; ++nj) {
        int n = (wave * 4 + nj) * 16 + l15;
        float cc = c_lds[n], ww = w_lds[n];
        #pragma unroll
        for (int mi = 0; mi < 4; ++mi)
          #pragma unroll
          for (int r = 0; r < 4; ++r)
            attp[mi * 4 + r] += fmaxf(acc[mi][nj][r] + cc, 0.f) * ww;
      }
      #pragma unroll
      for (int off = 1; off < 16; off <<= 1)
        #pragma unroll
        for (int q = 0; q < 16; ++q)
          attp[q] += __shfl_xor(attp[q], off, 64);
      if (l15 == 0) {
        #pragma unroll
        for (int mi = 0; mi < 4; ++mi)
          #pragma unroll
          for (int r = 0; r < 4; ++r)
            red[wave][mi * 16 + l4 * 4 + r] = attp[mi * 4 + r];
      }
    } else if (i < 7) {
      STAGE(ci + 1, cur ^ 1);                // producers: next chunk into other buffer
    }
    barrier_lgkm();

    if (tid < 64) {
      float av = red[0][tid] + red[1][tid] + red[2][tid] + red[3][tid]
               + red[4][tid] + red[5][tid] + red[6][tid] + red[7][tid];
      att_out[b * 4096 + (ci & 63) * 64 + tid] = av;   // b_att omitted: cancels in softmax
      float m = av;
      #pragma unroll
      for (int off = 32; off >= 1; off >>= 1) m = fmaxf(m, __shfl_xor(m, off, 64));
      p_lds[tid] = expf(av - m);
      if (tid == 0) m_out[ci] = m;
    }
    barrier_lgkm();

    // ---- pw[e] = sum_s exp(att_s - m_blk) * input[s][e] (bf16 from LDS, compute waves) ----
    float pw0 = 0.f, pw1 = 0.f;
    const int c = tid & 255, h = tid >> 8;   // h: 0,1 for tid<512
    if (tid < 512) {
      #pragma unroll 8
      for (int s = h * 32; s < h * 32 + 32; ++s) {
        float p = p_lds[s];
        unsigned int u = *(const unsigned int*)(Ab + s * 1024 + ((c * 4) ^ ((s & 7) << 4)));
        pw0 += p * lo_bf(u);
        pw1 += p * hi_bf(u);
      }
      if (h == 1) { redf[c * 2] = pw0; redf[c * 2 + 1] = pw1; }
    }
    barrier_lgkm();
    if (tid < 256) {
      pw_out[ci * 512 + c * 2]     = pw0 + redf[c * 2];
      pw_out[ci * 512 + c * 2 + 1] = pw1 + redf[c * 2 + 1];
    }
    cur ^= 1;
  }
}

// ---------- finalize: per-batch global softmax + rescaled partial-sum reduction ----------
__global__ void finalize(const float* __restrict__ att, const float* __restrict__ m_blk,
                         const float* __restrict__ pw, float* __restrict__ out) {
  const int bg = blockIdx.x;                 // 128 blocks = 32 b x 4 groups
  const int b = bg >> 2, g = bg & 3;
  const int tid = threadIdx.x;               // 256
  const int wave = tid >> 6, lane = tid & 63;
  __shared__ float wred[4];
  __shared__ float zred[4];
  __shared__ float fac[64];

  float v[16];
  float mx = -3.4e38f;
  #pragma unroll
  for (int i = 0; i < 16; ++i) {
    v[i] = att[b * 4096 + i * 256 + tid];
    mx = fmaxf(mx, v[i]);
  }
  #pragma unroll
  for (int off = 32; off >= 1; off >>= 1) mx = fmaxf(mx, __shfl_xor(mx, off, 64));
  if (lane == 0) wred[wave] = mx;
  __syncthreads();
  mx = fmaxf(fmaxf(wred[0], wred[1]), fmaxf(wred[2], wred[3]));

  float z = 0.f;
  #pragma unroll
  for (int i = 0; i < 16; ++i) { v[i] = expf(v[i] - mx); z += v[i]; }
  #pragma unroll
  for (int off = 32; off >= 1; off >>= 1) z += __shfl_xor(z, off, 64);
  if (lane == 0) zred[wave] = z;
  __syncthreads();
  z = zred[0] + zred[1] + zred[2] + zred[3];
  float invZ = 1.f / z;

  #pragma unroll
  for (int i = 0; i < 4; ++i) {
    int ii = g * 4 + i;
    out[16384 + b * 4096 + ii * 256 + tid] = v[ii] * invZ;   // prob (this block's quarter)
  }

  if (tid < 64) fac[tid] = expf(m_blk[b * 64 + tid] - mx) * invZ;
  __syncthreads();

  int col = g * 128 + (tid >> 1);
  int h = tid & 1;
  float w0 = 0.f;
  #pragma unroll 8
  for (int s = h * 32; s < h * 32 + 32; ++s)
    w0 += fac[s] * pw[(b * 64 + s) * 512 + col];
  w0 += __shfl_xor(w0, 1, 64);
  if (h == 0) out[b * 512 + col] = w0;                       // weighted
}

extern "C" void kernel_launch(void* const* d_in, const int* in_sizes, int n_in,
                              void* d_out, int out_size, void* d_ws, size_t ws_size,
                              hipStream_t stream) {
  const float* input = (const float*)d_in[0];
  const float* dec_h = (const float*)d_in[1];
  const float* W_enc = (const float*)d_in[2];
  const float* b_enc = (const float*)d_in[3];
  const float* W_dec = (const float*)d_in[4];
  const float* b_dec = (const float*)d_in[5];
  const float* w_att = (const float*)d_in[6];
  // d_in[7] = b_att: constant shift of logits, cancels in softmax.
  float* out = (float*)d_out;

  char* ws = (char*)d_ws;
  unsigned short* Wf = (unsigned short*)(ws);           // 512 KB  fragment-ordered bf16 W_enc^T
  float* cpart = (float*)(ws + 524288);                 // 256 KB  dec_att partials [4][32][512]
  float* att   = (float*)(ws + 786432);                 // 512 KB  logits [32][4096]
  float* m_b   = (float*)(ws + 1310720);                // 8 KB    per-chunk max [2048]
  float* pw    = (float*)(ws + 1318912);                // 4 MB    partial weighted [2048][512]

  hipLaunchKernelGGL(prep_w, dim3(128), dim3(256), 0, stream, W_enc, Wf);
  hipLaunchKernelGGL(prep_c, dim3(128), dim3(512), 0, stream, dec_h, W_dec, b_dec, b_enc, cpart);
  hipLaunchKernelGGL(attn_main, dim3(256), dim3(1024), 0, stream, input, Wf, cpart, w_att, att, m_b, pw);
  hipLaunchKernelGGL(finalize, dim3(128), dim3(256), 0, stream, att, m_b, pw, out);
}